// Round 5
// baseline (245.669 us; speedup 1.0000x reference)
//
#include <hip/hip_runtime.h>

// MAMBA chunk scan — Round 9: 2 blocks/CU (r8 was grid==CU-count -> structurally
// 1 block/CU, Occ 18%, all latency exposed).
//   out[m,p] = exp(dA[m]) * ( C[m,:]@prev[p,:]^T                      (inter, K=128)
//             + sum_{k<=m} cb[m,k]*(exp(-dA[k])*dt[k]*x[k,p])         (intra, K<=256)
//             + D[h]*x[m,p]*exp(-dA[m]) )                             (diag, acc-init)
// Changes vs r8 (64us rocprof, VGPR=120, FETCH 54.7MB, Occ 18%):
//  - block = (b,c,head-PAIR), grid 512 -> 2 blocks/CU (LDS 2x51.2=102.4KB<160,
//    VGPR 120<=128 = 4 waves/SIMD). 16 waves/CU; cross-block slippage fills
//    barrier + commit-VALU gaps (m114 MFMA/VALU co-scheduling).
//  - persistent h-invariant cb/C bf16 fragments kept (amortized 2x now).
//  - launch_bounds(512,4): pin the 128-VGPR ceiling 2-blocks/CU needs.
//  - XCD swizzle chunk=64: each XCD owns 4 full (b,c) groups -> cb/C L2-shared.
// B=2 S=4096 CS=256 H=32 G=1 P=64 N=128 NC=16

typedef unsigned short u16;
typedef __bf16 v8bf __attribute__((ext_vector_type(8)));
typedef unsigned short v8u16 __attribute__((ext_vector_type(8)));
typedef float v4f __attribute__((ext_vector_type(4)));

#define LDB 264  // sB u16 row stride; 132 dw == 4 mod 32 (verified conflict-floor class)
#define LDP 136  // sP u16 row stride; 68 dw == 4 mod 32

__device__ __forceinline__ unsigned pk2f(float a, float b) {
  u16 x = __builtin_bit_cast(u16, (__bf16)a);
  u16 y = __builtin_bit_cast(u16, (__bf16)b);
  return (unsigned)x | ((unsigned)y << 16);
}
__device__ __forceinline__ v8bf cvt8(float4 lo, float4 hi) {
  v8bf r;
  r[0] = (__bf16)lo.x; r[1] = (__bf16)lo.y; r[2] = (__bf16)lo.z; r[3] = (__bf16)lo.w;
  r[4] = (__bf16)hi.x; r[5] = (__bf16)hi.y; r[6] = (__bf16)hi.z; r[7] = (__bf16)hi.w;
  return r;
}
__device__ __forceinline__ v8bf cvt8_mask(float4 lo, float4 hi, int k0, int m) {
  const float av[8] = {lo.x, lo.y, lo.z, lo.w, hi.x, hi.y, hi.z, hi.w};
  v8bf r;
#pragma unroll
  for (int j = 0; j < 8; j++) r[j] = (__bf16)((k0 + j <= m) ? av[j] : 0.f);
  return r;
}

struct SR {  // per-head stage registers (ping-pong pair, static-indexed only)
  float4 pf[4];            // prev, coalesced
  float4 dA4[2], dt4[2];   // lane's m-rows
  float xv[2][4][4];       // x[m,p] in C/D fragment layout [tt][r][pt]
};

__global__ __launch_bounds__(512, 4) void mamba_cs_kernel(
    const float* __restrict__ cbp,   // (2,16,1,256,256)
    const float* __restrict__ xp,    // (2,4096,32,64)
    const float* __restrict__ dtp,   // (2,32,16,256)
    const float* __restrict__ dAp,   // (2,32,16,256)
    const float* __restrict__ Cp,    // (2,4096,1,128)
    const float* __restrict__ pvp,   // (2,16,32,64,128)
    const float* __restrict__ Dp,    // (32,)
    float* __restrict__ outp)        // (2,4096,32,64)
{
  __shared__ u16 sB[64 * LDB];  // w-scaled x^T bf16: [p][k], 33792B
  __shared__ u16 sP[64 * LDP];  // prev bf16: [p][n], 17408B  (51200B -> 2 blk/CU)

  // XCD-chunked swizzle, chunk 64 (bijective: 512 % 8 == 0)
  const int bid0 = blockIdx.x;
  const int wg = ((bid0 & 7) << 6) | (bid0 >> 3);
  const int hp = wg & 15;           // head-pair index
  const int c = (wg >> 4) & 15;
  const int b = wg >> 8;
  const int h0 = hp * 2;

  const int t = threadIdx.x;
  const int lane = t & 63;
  const int wid = t >> 6;           // 0..7
  const int row = lane & 15;
  const int q = lane >> 4;
  const int qo = q * 8;

  // paired 16-row tiles for triangle balance: wave w -> tiles (w, 15-w)
  const int Ta = wid;
  const int Tb = 15 - wid;
  const int ma = Ta * 16 + row;
  const int mb = Tb * 16 + row;
  const int kfa = Ta >> 1;
  const int kfb = Tb >> 1;

  const float* CBbase = cbp + (size_t)(b * 16 + c) * 65536;
  const float* Cbase  = Cp + (size_t)(b * 4096 + c * 256) * 128;

  // ---- persistent h-independent A-fragments (loaded once per block) ----
  const float* Cra = Cbase + (size_t)ma * 128;
  const float* Crb = Cbase + (size_t)mb * 128;
  const float* cba = CBbase + (size_t)ma * 256;
  const float* cbb = CBbase + (size_t)mb * 256;

  v8bf Ca[4], Cb2[4];  // inter A-frags, tiles a/b
  v8bf Aa[4], Ab[8];   // intra A-frags (masked at diagonal), tiles a/b
#pragma unroll
  for (int kf = 0; kf < 4; ++kf) {
    const int no = kf * 32 + qo;
    Ca[kf]  = cvt8(*(const float4*)(Cra + no), *(const float4*)(Cra + no + 4));
    Cb2[kf] = cvt8(*(const float4*)(Crb + no), *(const float4*)(Crb + no + 4));
  }
#pragma unroll
  for (int kf = 0; kf < 4; ++kf)
    if (kf <= kfa) {
      const int ko = kf * 32 + qo;
      const float4 lo = *(const float4*)(cba + ko);
      const float4 hi = *(const float4*)(cba + ko + 4);
      Aa[kf] = (kf == kfa) ? cvt8_mask(lo, hi, ko, ma) : cvt8(lo, hi);
    }
#pragma unroll
  for (int kf = 0; kf < 8; ++kf)
    if (kf <= kfb) {
      const int ko = kf * 32 + qo;
      const float4 lo = *(const float4*)(cbb + ko);
      const float4 hi = *(const float4*)(cbb + ko + 4);
      Ab[kf] = (kf == kfb) ? cvt8_mask(lo, hi, ko, mb) : cvt8(lo, hi);
    }

  v4f acc[2][4];
  float4 dAq[2];

  auto stage_load = [&](int h, SR& R) {
    const float4* Pv = (const float4*)(pvp + (size_t)((b * 16 + c) * 32 + h) * 8192);
#pragma unroll
    for (int i = 0; i < 4; i++) R.pf[i] = Pv[i * 512 + t];
    const int bhc = ((b * 32 + h) * 16 + c) * 256;
    const float* Xb = xp + ((size_t)(b * 4096 + c * 256) * 32 + h) * 64;
#pragma unroll
    for (int tt = 0; tt < 2; ++tt) {
      const int m4 = (tt ? Tb : Ta) * 16 + q * 4;
      R.dA4[tt] = *(const float4*)(dAp + bhc + m4);
      R.dt4[tt] = *(const float4*)(dtp + bhc + m4);
#pragma unroll
      for (int r = 0; r < 4; ++r) {
        const float* xr = Xb + (size_t)(m4 + r) * 2048 + row;
#pragma unroll
        for (int pt = 0; pt < 4; ++pt) R.xv[tt][r][pt] = xr[pt * 16];
      }
    }
  };

  auto commit = [&](SR& R, float Dh) {
    // prev -> sP (bf16)
#pragma unroll
    for (int i = 0; i < 4; i++) {
      const int idx = i * 512 + t, prow = idx >> 5, c4 = idx & 31;
      u16* s = &sP[prow * LDP + c4 * 4];
      *(unsigned*)(s)     = pk2f(R.pf[i].x, R.pf[i].y);
      *(unsigned*)(s + 2) = pk2f(R.pf[i].z, R.pf[i].w);
    }
    // x*w -> sB, acc init = Dh*x*exp(-dA[m])
#pragma unroll
    for (int tt = 0; tt < 2; ++tt) {
      const int m4 = (tt ? Tb : Ta) * 16 + q * 4;
      dAq[tt] = R.dA4[tt];
      const float dv[4] = {R.dA4[tt].x, R.dA4[tt].y, R.dA4[tt].z, R.dA4[tt].w};
      const float tv[4] = {R.dt4[tt].x, R.dt4[tt].y, R.dt4[tt].z, R.dt4[tt].w};
      float wi[4], w[4];
#pragma unroll
      for (int r = 0; r < 4; ++r) {
        wi[r] = __expf(-dv[r]);
        w[r] = wi[r] * tv[r];
      }
#pragma unroll
      for (int pt = 0; pt < 4; ++pt) {
        v4f a;
#pragma unroll
        for (int r = 0; r < 4; ++r) a[r] = Dh * R.xv[tt][r][pt] * wi[r];
        acc[tt][pt] = a;
        u16* srow = &sB[(pt * 16 + row) * LDB + m4];
        *(unsigned*)(srow)     = pk2f(w[0] * R.xv[tt][0][pt], w[1] * R.xv[tt][1][pt]);
        *(unsigned*)(srow + 2) = pk2f(w[2] * R.xv[tt][2][pt], w[3] * R.xv[tt][3][pt]);
      }
    }
  };

  auto compute = [&]() {
    // inter: A = persistent C-frags, B = sP
#pragma unroll
    for (int kf = 0; kf < 4; ++kf) {
      const int no = kf * 32 + qo;
      v8bf bf[4];
#pragma unroll
      for (int pt = 0; pt < 4; ++pt)
        bf[pt] = __builtin_bit_cast(v8bf, *(const v8u16*)&sP[(pt * 16 + row) * LDP + no]);
#pragma unroll
      for (int pt = 0; pt < 4; ++pt) {
        acc[0][pt] = __builtin_amdgcn_mfma_f32_16x16x32_bf16(Ca[kf], bf[pt], acc[0][pt], 0, 0, 0);
        acc[1][pt] = __builtin_amdgcn_mfma_f32_16x16x32_bf16(Cb2[kf], bf[pt], acc[1][pt], 0, 0, 0);
      }
    }
    // intra: A = persistent cb-frags, B = sB, causal
#pragma unroll
    for (int kf = 0; kf < 8; ++kf) {
      if (kf <= kfb) {
        const int ko = kf * 32 + qo;
        v8bf bf[4];
#pragma unroll
        for (int pt = 0; pt < 4; ++pt)
          bf[pt] = __builtin_bit_cast(v8bf, *(const v8u16*)&sB[(pt * 16 + row) * LDB + ko]);
#pragma unroll
        for (int pt = 0; pt < 4; ++pt)
          acc[1][pt] = __builtin_amdgcn_mfma_f32_16x16x32_bf16(Ab[kf], bf[pt], acc[1][pt], 0, 0, 0);
        if (kf <= kfa) {
#pragma unroll
          for (int pt = 0; pt < 4; ++pt)
            acc[0][pt] = __builtin_amdgcn_mfma_f32_16x16x32_bf16(Aa[kf], bf[pt], acc[0][pt], 0, 0, 0);
        }
      }
    }
  };

  auto epilogue = [&](int h) {
    float* Ob = outp + ((size_t)(b * 4096 + c * 256) * 32 + h) * 64;
#pragma unroll
    for (int tt = 0; tt < 2; ++tt) {
      const int mBase = (tt ? Tb : Ta) * 16 + q * 4;
      const float ev[4] = {dAq[tt].x, dAq[tt].y, dAq[tt].z, dAq[tt].w};
#pragma unroll
      for (int r = 0; r < 4; ++r) {
        const float e = __expf(ev[r]);
        float* orow = Ob + (size_t)(mBase + r) * 2048 + row;
#pragma unroll
        for (int pt = 0; pt < 4; ++pt) orow[pt * 16] = acc[tt][pt][r] * e;
      }
    }
  };

  const float D0 = Dp[h0], D1 = Dp[h0 + 1];

  SR RA, RB;
  stage_load(h0, RA);

  // h0
  commit(RA, D0);
  __syncthreads();
  stage_load(h0 + 1, RB);   // hidden under compute
  compute();
  epilogue(h0);
  __syncthreads();

  // h1
  commit(RB, D1);
  __syncthreads();
  compute();
  epilogue(h0 + 1);
}

extern "C" void kernel_launch(void* const* d_in, const int* in_sizes, int n_in,
                              void* d_out, int out_size, void* d_ws, size_t ws_size,
                              hipStream_t stream) {
  const float* cb = (const float*)d_in[0];
  const float* x = (const float*)d_in[1];
  const float* dt = (const float*)d_in[2];
  const float* dA = (const float*)d_in[3];
  const float* C = (const float*)d_in[4];
  const float* pv = (const float*)d_in[5];
  const float* D = (const float*)d_in[6];
  float* out = (float*)d_out;
  // grid 512: block = (b,c,head-pair); 2 blocks/CU
  mamba_cs_kernel<<<dim3(512), dim3(512), 0, stream>>>(cb, x, dt, dA, C, pv, D, out);
}

// Round 7
// 181.727 us; speedup vs baseline: 1.3519x; 1.3519x over previous
//
#include <hip/hip_runtime.h>

// MAMBA chunk scan — Round 11 (= r10 resubmit after infra flake; code-size
// hardened: rolled 4-head loop, hoisted D loads. Same theory/predictions.)
//   out[m,p] = exp(dA[m]) * ( C[m,:]@prev[p,:]^T                      (inter, K=128)
//             + sum_{k<=m} cb[m,k]*(exp(-dA[k])*dt[k]*x[k,p])         (intra, K<=256)
//             + D[h]*x[m,p]*exp(-dA[m]) )                             (diag, acc-init)
// r9 post-mortem: launch_bounds cap 128 < fat-block demand (~260) -> VGPR 64 +
// catastrophic scratch spill (WRITE 210MB). Fat waves are stuck at 2 waves/SIMD.
// r10/r11: halve per-wave state instead of capping it:
//  - 1024 threads / 16 waves, ONE 16-row m-tile per wave (acc 16 regs, xv 16).
//  - persistent cb frags DROPPED (the register hog): cb re-read per head from
//    L2 (XCD swizzle keeps the 256KB tile L2-resident, shared by 8 blocks/XCD);
//    ~200cyc L2 latency hidden by 4 waves/SIMD TLP. C-frags (16 regs) kept.
//  - single SR stage buffer (commit drains SR before next stage_load overwrites)
//    -> ~110 VGPR total, under the 128 cap of __launch_bounds__(1024,4).
//    Diagnostic: WRITE_SIZE must be ~66MB (no spill).
//  - T14 kept: next head's stage loads issued right after barrier, hidden
//    under compute. 2 barriers/head.
// B=2 S=4096 CS=256 H=32 G=1 P=64 N=128 NC=16

typedef unsigned short u16;
typedef __bf16 v8bf __attribute__((ext_vector_type(8)));
typedef unsigned short v8u16 __attribute__((ext_vector_type(8)));
typedef float v4f __attribute__((ext_vector_type(4)));
typedef unsigned v2u __attribute__((ext_vector_type(2)));

#define LDB 264  // sB u16 row stride; 132 dw == 4 mod 32 (verified conflict-floor class)
#define LDP 136  // sP u16 row stride; 68 dw == 4 mod 32

__device__ __forceinline__ unsigned pk2f(float a, float b) {
  u16 x = __builtin_bit_cast(u16, (__bf16)a);
  u16 y = __builtin_bit_cast(u16, (__bf16)b);
  return (unsigned)x | ((unsigned)y << 16);
}
__device__ __forceinline__ v8bf cvt8(float4 lo, float4 hi) {
  v8bf r;
  r[0] = (__bf16)lo.x; r[1] = (__bf16)lo.y; r[2] = (__bf16)lo.z; r[3] = (__bf16)lo.w;
  r[4] = (__bf16)hi.x; r[5] = (__bf16)hi.y; r[6] = (__bf16)hi.z; r[7] = (__bf16)hi.w;
  return r;
}
__device__ __forceinline__ v8bf cvt8_mask(float4 lo, float4 hi, int k0, int m) {
  const float av[8] = {lo.x, lo.y, lo.z, lo.w, hi.x, hi.y, hi.z, hi.w};
  v8bf r;
#pragma unroll
  for (int j = 0; j < 8; j++) r[j] = (__bf16)((k0 + j <= m) ? av[j] : 0.f);
  return r;
}

__global__ __launch_bounds__(1024, 4) void mamba_cs_kernel(
    const float* __restrict__ cbp,   // (2,16,1,256,256)
    const float* __restrict__ xp,    // (2,4096,32,64)
    const float* __restrict__ dtp,   // (2,32,16,256)
    const float* __restrict__ dAp,   // (2,32,16,256)
    const float* __restrict__ Cp,    // (2,4096,1,128)
    const float* __restrict__ pvp,   // (2,16,32,64,128)
    const float* __restrict__ Dp,    // (32,)
    float* __restrict__ outp)        // (2,4096,32,64)
{
  __shared__ u16 sB[64 * LDB];  // w-scaled x^T bf16: [p][k], 33792B
  __shared__ u16 sP[64 * LDP];  // prev bf16: [p][n], 17408B  (51200B total)

  // XCD-chunked swizzle, chunk 32 (bijective: 256 % 8 == 0)
  const int bid0 = blockIdx.x;
  const int wg = ((bid0 & 7) << 5) | (bid0 >> 3);
  const int hg = wg & 7;            // 4-head group
  const int c = (wg >> 3) & 15;
  const int b = wg >> 7;
  const int h0 = hg * 4;

  const int t = threadIdx.x;
  const int lane = t & 63;
  const int wid = t >> 6;           // 0..15 = this wave's m-tile
  const int row = lane & 15;
  const int q = lane >> 4;
  const int qo = q * 8;

  const int T = wid;
  const int ma = T * 16 + row;      // lane's A-row
  const int m4 = T * 16 + q * 4;    // lane's first C/D-row
  const int kfa = T >> 1;           // last (diagonal) intra k-block

  const float* CBbase = cbp + (size_t)(b * 16 + c) * 65536;
  const float* cba = CBbase + (size_t)ma * 256;
  const float* Cra = Cp + (size_t)(b * 4096 + c * 256) * 128 + (size_t)ma * 128;

  // ---- persistent h-independent inter A-fragments (16 VGPR) ----
  v8bf Ca[4];
#pragma unroll
  for (int kf = 0; kf < 4; ++kf) {
    const int no = kf * 32 + qo;
    Ca[kf] = cvt8(*(const float4*)(Cra + no), *(const float4*)(Cra + no + 4));
  }

  const float4 Dv = *(const float4*)(Dp + h0);  // 4 heads' D
  const float Dhs[4] = {Dv.x, Dv.y, Dv.z, Dv.w};

  // ---- stage registers (single buffer; commit drains before next load) ----
  float4 pf0, pf1, dA4, dt4;
  float xv[4][4];  // [r][pt]
  v4f acc[4];
  float4 dAq;

  auto stage_load = [&](int h) {
    const float4* Pv = (const float4*)(pvp + (size_t)((b * 16 + c) * 32 + h) * 8192);
    pf0 = Pv[t];
    pf1 = Pv[1024 + t];
    const int bhc = ((b * 32 + h) * 16 + c) * 256;
    dA4 = *(const float4*)(dAp + bhc + m4);
    dt4 = *(const float4*)(dtp + bhc + m4);
    const float* Xb = xp + ((size_t)(b * 4096 + c * 256) * 32 + h) * 64;
#pragma unroll
    for (int r = 0; r < 4; ++r) {
      const float* xr = Xb + (size_t)(m4 + r) * 2048 + row;
#pragma unroll
      for (int pt = 0; pt < 4; ++pt) xv[r][pt] = xr[pt * 16];
    }
  };

  auto commit = [&](float Dh) {
    // prev -> sP (bf16), 2 x ds_write_b64
#pragma unroll
    for (int j = 0; j < 2; ++j) {
      const int idx = j * 1024 + t, prow = idx >> 5, c4 = idx & 31;
      const float4 p4 = j ? pf1 : pf0;
      v2u wv;
      wv[0] = pk2f(p4.x, p4.y);
      wv[1] = pk2f(p4.z, p4.w);
      *(v2u*)&sP[prow * LDP + c4 * 4] = wv;
    }
    // x*w -> sB (lane-exact), acc init = Dh*x*exp(-dA[m])
    dAq = dA4;
    const float dv[4] = {dA4.x, dA4.y, dA4.z, dA4.w};
    const float tv[4] = {dt4.x, dt4.y, dt4.z, dt4.w};
    float wi[4], w[4];
#pragma unroll
    for (int r = 0; r < 4; ++r) {
      wi[r] = __expf(-dv[r]);
      w[r] = wi[r] * tv[r];
    }
#pragma unroll
    for (int pt = 0; pt < 4; ++pt) {
      v4f a;
#pragma unroll
      for (int r = 0; r < 4; ++r) a[r] = Dh * xv[r][pt] * wi[r];
      acc[pt] = a;
      v2u wv;
      wv[0] = pk2f(w[0] * xv[0][pt], w[1] * xv[1][pt]);
      wv[1] = pk2f(w[2] * xv[2][pt], w[3] * xv[3][pt]);
      *(v2u*)&sB[(pt * 16 + row) * LDB + m4] = wv;
    }
  };

  auto compute = [&]() {
    // inter: A = persistent C-frags, B = sP (LDS)
#pragma unroll
    for (int kf = 0; kf < 4; ++kf) {
      const int no = kf * 32 + qo;
      v8bf bf[4];
#pragma unroll
      for (int pt = 0; pt < 4; ++pt)
        bf[pt] = __builtin_bit_cast(v8bf, *(const v8u16*)&sP[(pt * 16 + row) * LDP + no]);
#pragma unroll
      for (int pt = 0; pt < 4; ++pt)
        acc[pt] = __builtin_amdgcn_mfma_f32_16x16x32_bf16(Ca[kf], bf[pt], acc[pt], 0, 0, 0);
    }
    // intra: A = cb row from L2 (masked at diagonal), B = sB (LDS), causal
#pragma unroll
    for (int kf = 0; kf < 8; ++kf) {
      if (kf <= kfa) {  // wave-uniform guard
        const int ko = kf * 32 + qo;
        const float4 lo = *(const float4*)(cba + ko);
        const float4 hi = *(const float4*)(cba + ko + 4);
        v8bf bf[4];
#pragma unroll
        for (int pt = 0; pt < 4; ++pt)
          bf[pt] = __builtin_bit_cast(v8bf, *(const v8u16*)&sB[(pt * 16 + row) * LDB + ko]);
        const v8bf a = (kf == kfa) ? cvt8_mask(lo, hi, ko, ma) : cvt8(lo, hi);
#pragma unroll
        for (int pt = 0; pt < 4; ++pt)
          acc[pt] = __builtin_amdgcn_mfma_f32_16x16x32_bf16(a, bf[pt], acc[pt], 0, 0, 0);
      }
    }
  };

  auto epilogue = [&](int h) {
    float* Ob = outp + ((size_t)(b * 4096 + c * 256) * 32 + h) * 64;
    const float ev[4] = {dAq.x, dAq.y, dAq.z, dAq.w};
#pragma unroll
    for (int r = 0; r < 4; ++r) {
      const float e = __expf(ev[r]);
      float* orow = Ob + (size_t)(m4 + r) * 2048 + row;
#pragma unroll
      for (int pt = 0; pt < 4; ++pt) orow[pt * 16] = acc[pt][r] * e;
    }
  };

  stage_load(h0);
  for (int hh = 0; hh < 4; ++hh) {   // rolled: smaller body, state is scalar/static
    commit(Dhs[hh]);
    __syncthreads();
    if (hh < 3) stage_load(h0 + hh + 1);  // T14: hidden under compute
    compute();
    epilogue(h0 + hh);
    if (hh < 3) __syncthreads();
  }
}

extern "C" void kernel_launch(void* const* d_in, const int* in_sizes, int n_in,
                              void* d_out, int out_size, void* d_ws, size_t ws_size,
                              hipStream_t stream) {
  const float* cb = (const float*)d_in[0];
  const float* x = (const float*)d_in[1];
  const float* dt = (const float*)d_in[2];
  const float* dA = (const float*)d_in[3];
  const float* C = (const float*)d_in[4];
  const float* pv = (const float*)d_in[5];
  const float* D = (const float*)d_in[6];
  float* out = (float*)d_out;
  // grid 256: block = (b,c,4-head group); 1024 thr = 16 waves/CU
  mamba_cs_kernel<<<dim3(256), dim3(1024), 0, stream>>>(cb, x, dt, dA, C, pv, D, out);
}